// Round 4
// baseline (2685.185 us; speedup 1.0000x reference)
//
#include <hip/hip_runtime.h>
#include <hip/hip_bf16.h>

// HINGE_56985626083396 — fused embedding-conv-BN-min-FC forward on MI355X.
//
// Round-13: demand == unique. Law from r8-r12: dur ~= FETCH/0.45 TB/s on the
// scattered gather path; FETCH ~= gather demand that L3 can't absorb. r12's
// merged passA demanded 786 MB (K=1280 re-gathers hrt x4; n-siblings x2) ->
// FETCH 270 MB. This round gathers every embedding row EXACTLY ONCE per pass:
//   - block = 32 batches x full N=512 (no n-siblings).
//   - hrt GEMM with REPLICATED A rows (row m -> batch m/4): H and m1 get the
//     same (b,f)->thread mapping as the t GEMM, so they stay in registers.
//     No Hbuf, no min1 buffers, no H in LDS.
//   - hrt phase (K=768, gathered once; 2nd n-half re-read is L2-hot) feeds
//     H (W2[:,0:768]) + V0/U/V1 (W1 cols) -> G1 windows = V_kk + U.
//   - t phase: ONE K=512 GEMM, wave tile 64x128 (acc 128 VGPR), 4 windows
//     land in acc regs r=0..3 of the same thread.
//   - T14 prefetch: next chunk's A-gather issued before MFMA, LDS-written
//     after the post-MFMA barrier (hides miss latency at 1 block/CU).
// passA: stats (sums/sumsq via LDS red -> accum). passB: m1(in-reg, coef) +
// m2(min over r) + dot(fcw) -> outacc atomics.
// Demand per pass = 5.5 KB/batch = 180 MB (unique 51.2 MB bf16 tables).
// ws: bf16 tables + W = 53.2 MB <= proven 69.1 MB floor. conv biases skipped
// (BN mean-subtraction cancels them exactly).

typedef __hip_bfloat16 bf16;
typedef short bf16x8 __attribute__((ext_vector_type(8)));   // 8 bf16 in 4 VGPRs
typedef float f32x4 __attribute__((ext_vector_type(4)));

#define BATCH 32768

__device__ __forceinline__ unsigned short f2b(float f) {
    union { float f; unsigned u; } v; v.f = f;
    unsigned r = v.u + 0x7fffu + ((v.u >> 16) & 1u);   // round-to-nearest-even
    return (unsigned short)(r >> 16);
}

__device__ __forceinline__ float b2f(unsigned short u) {
    union { unsigned x; float f; } v; v.x = ((unsigned)u) << 16;
    return v.f;
}

__global__ __launch_bounds__(256)
void cvt_kernel(const float* __restrict__ src, unsigned short* __restrict__ dst, int n4)
{
    int i = blockIdx.x * 256 + threadIdx.x;
    if (i >= n4) return;
    float4 v = ((const float4*)src)[i];
    ushort4 h;
    h.x = f2b(v.x); h.y = f2b(v.y); h.z = f2b(v.z); h.w = f2b(v.w);
    ((ushort4*)dst)[i] = h;
}

// One block: 32 batches, N=512. 512 threads, 8 waves (2 m-rows x 4 n-cols).
// hrt phase: A rows replicated x4 (arow = m>>2), wave tile 64x64 per n-half.
// t phase:   A rows = 4/batch (b=m>>2, kk=m&3), wave tile 64x128 full-N.
template<bool FINAL>
__global__ __launch_bounds__(512, 2)
void pass_kernel(const int* __restrict__ x, const bf16* __restrict__ embR,
                 const bf16* __restrict__ embV, const bf16* __restrict__ W1b,
                 const bf16* __restrict__ W2b, float* __restrict__ accum,
                 const float* __restrict__ coef, const float* __restrict__ fcw,
                 float* __restrict__ outacc)
{
    __shared__ __align__(16) short Ash[128 * 72];   // +8 pad per row
    __shared__ __align__(16) short Bsh[512 * 72];
    __shared__ int xsh[384];
    __shared__ float red[6144];                     // [s|q][6 kw][512 f]

    const int tid = threadIdx.x;
    const int b0 = blockIdx.x * 32;

    for (int i = tid; i < 384; i += 512) xsh[i] = x[b0 * 12 + i];
    if constexpr (!FINAL)
        for (int i = tid; i < 6144; i += 512) red[i] = 0.f;
    __syncthreads();

    const int lane = tid & 63;
    const int wv   = tid >> 6;                      // 0..7
    const int wmb  = (wv >> 2) * 64;                // wave m-offset (0/64)
    const int wnb  = (wv & 3) * 64;                 // wave n-offset in 256-half
    const int quad = lane >> 4;
    const int l16  = lane & 15;

    // ---------------- staging helpers ----------------
    auto loadA_hrt = [&](int ch, uint4& v) {        // 32 rows x 64 k
        if (tid < 256) {
            int row = tid >> 3, off8 = tid & 7, seg = ch >> 2;
            int idx; const bf16* tab;
            if (seg == 0)      { idx = xsh[row * 12 + 1]; tab = embV; }  // fv0
            else if (seg == 1) { idx = xsh[row * 12 + 0]; tab = embR; }  // fr0
            else               { idx = xsh[row * 12 + 3]; tab = embV; }  // fv1
            v = *((const uint4*)(tab + (size_t)idx * 256 + (ch & 3) * 64) + off8);
        }
    };
    auto writeA_hrt = [&](const uint4& v) {
        if (tid < 256) {
            int row = tid >> 3, off8 = tid & 7;
            *(uint4*)&Ash[row * 72 + off8 * 8] = v;
        }
    };
    auto loadA_t = [&](int ch, uint4& v0, uint4& v1) {  // 128 rows x 64 k
        int seg = ch >> 2;                              // 0: kr, 1: kv
        int off8 = tid & 7;
        {
            int row = tid >> 3;
            int idx = xsh[(row >> 2) * 12 + 2 * (row & 3) + 4 + seg];
            const bf16* tab = seg ? embV : embR;
            v0 = *((const uint4*)(tab + (size_t)idx * 256 + (ch & 3) * 64) + off8);
        }
        {
            int row = (tid >> 3) + 64;
            int idx = xsh[(row >> 2) * 12 + 2 * (row & 3) + 4 + seg];
            const bf16* tab = seg ? embV : embR;
            v1 = *((const uint4*)(tab + (size_t)idx * 256 + (ch & 3) * 64) + off8);
        }
    };
    auto writeA_t = [&](const uint4& v0, const uint4& v1) {
        int row = tid >> 3, off8 = tid & 7;
        *(uint4*)&Ash[row * 72 + off8 * 8] = v0;
        *(uint4*)&Ash[(row + 64) * 72 + off8 * 8] = v1;
    };
    auto stageB256 = [&](short* dst, const bf16* W, int stride, int col0) {
        #pragma unroll
        for (int i = 0; i < 4; ++i) {
            int flat = tid + i * 512, fr = flat >> 3, off8 = flat & 7;
            uint4 v = *((const uint4*)(W + (size_t)fr * stride + col0) + off8);
            *(uint4*)&dst[fr * 72 + off8 * 8] = v;
        }
    };
    auto stageB512 = [&](int col0) {                // W2b, full 512 f
        #pragma unroll
        for (int i = 0; i < 8; ++i) {
            int flat = tid + i * 512, fr = flat >> 3, off8 = flat & 7;
            uint4 v = *((const uint4*)(W2b + (size_t)fr * 1280 + col0) + off8);
            *(uint4*)&Bsh[fr * 72 + off8 * 8] = v;
        }
    };

    // ---------------- MFMA helpers ----------------
    auto mma2 = [&](f32x4 (&aH)[4][4], f32x4 (&aV)[4][4]) {   // hrt: repl. A
        #pragma unroll
        for (int ks = 0; ks < 64; ks += 32) {
            bf16x8 af[4], bH[4], bV[4];
            #pragma unroll
            for (int t = 0; t < 4; ++t) {
                int arow = (wmb + t * 16 + l16) >> 2;
                af[t] = *(const bf16x8*)&Ash[arow * 72 + ks + quad * 8];
                int frow = wnb + t * 16 + l16;
                bH[t] = *(const bf16x8*)&Bsh[frow * 72 + ks + quad * 8];
                bV[t] = *(const bf16x8*)&Bsh[(256 + frow) * 72 + ks + quad * 8];
            }
            #pragma unroll
            for (int i = 0; i < 4; ++i)
                #pragma unroll
                for (int j = 0; j < 4; ++j) {
                    aH[i][j] = __builtin_amdgcn_mfma_f32_16x16x32_bf16(
                        af[i], bH[j], aH[i][j], 0, 0, 0);
                    aV[i][j] = __builtin_amdgcn_mfma_f32_16x16x32_bf16(
                        af[i], bV[j], aV[i][j], 0, 0, 0);
                }
        }
    };
    auto mma1 = [&](f32x4 (&aT)[4][8]) {                      // t: full N
        #pragma unroll
        for (int ks = 0; ks < 64; ks += 32) {
            bf16x8 af[4], bfr[8];
            #pragma unroll
            for (int t = 0; t < 4; ++t)
                af[t] = *(const bf16x8*)&Ash[(wmb + t * 16 + l16) * 72 + ks + quad * 8];
            #pragma unroll
            for (int j = 0; j < 8; ++j) {
                int frow = ((j >> 2) << 8) + wnb + ((j & 3) << 4) + l16;
                bfr[j] = *(const bf16x8*)&Bsh[frow * 72 + ks + quad * 8];
            }
            #pragma unroll
            for (int i = 0; i < 4; ++i)
                #pragma unroll
                for (int j = 0; j < 8; ++j)
                    aT[i][j] = __builtin_amdgcn_mfma_f32_16x16x32_bf16(
                        af[i], bfr[j], aT[i][j], 0, 0, 0);
        }
    };

    // ================= hrt phase (K=768, two n-halves) =================
    float    h_[2][4][4];       // passA: f32 H per (nh,i,j)
    unsigned hm[2][4][4];       // passB: packed {H bf16, m1 bf16}
    #pragma unroll
    for (int nh = 0; nh < 2; ++nh) {
        const int nb = nh * 256;
        f32x4 aH[4][4], aV[4][4];
        #pragma unroll
        for (int i = 0; i < 4; ++i)
            #pragma unroll
            for (int j = 0; j < 4; ++j) {
                aH[i][j] = (f32x4){0.f, 0.f, 0.f, 0.f};
                aV[i][j] = (f32x4){0.f, 0.f, 0.f, 0.f};
            }
        float v0_[4][4], u_[4][4];
        uint4 apf;
        loadA_hrt(0, apf);
        writeA_hrt(apf);
        #pragma unroll 1
        for (int ch = 0; ch < 12; ++ch) {
            if (ch < 11) loadA_hrt(ch + 1, apf);            // prefetch
            stageB256(Bsh, W2b + (size_t)nb * 1280, 1280, ch * 64);
            stageB256(Bsh + 256 * 72, W1b + (size_t)nb * 512, 512,
                      (ch >= 8) ? ch * 64 - 512 : ch * 64);
            __syncthreads();
            mma2(aH, aV);
            __syncthreads();
            if (ch < 11) writeA_hrt(apf);                   // write-late
            if (ch == 3) {                                  // V0 done
                #pragma unroll
                for (int i = 0; i < 4; ++i)
                    #pragma unroll
                    for (int j = 0; j < 4; ++j) {
                        v0_[i][j] = aV[i][j][0];
                        aV[i][j] = (f32x4){0.f, 0.f, 0.f, 0.f};
                    }
            } else if (ch == 7) {                           // U done
                #pragma unroll
                for (int i = 0; i < 4; ++i)
                    #pragma unroll
                    for (int j = 0; j < 4; ++j) {
                        u_[i][j] = aV[i][j][0];
                        aV[i][j] = (f32x4){0.f, 0.f, 0.f, 0.f};
                    }
            }
        }
        // epilogue: aV holds V1. o1w0 = V0+U, o1w1 = V1+U.
        #pragma unroll
        for (int j = 0; j < 4; ++j) {
            int f = nb + wnb + j * 16 + l16;
            if constexpr (!FINAL) {
                float s0 = 0.f, q0 = 0.f, s1 = 0.f, q1 = 0.f;
                #pragma unroll
                for (int i = 0; i < 4; ++i) {
                    float o0 = v0_[i][j] + u_[i][j];
                    float o1 = aV[i][j][0] + u_[i][j];
                    s0 += o0; q0 += o0 * o0;
                    s1 += o1; q1 += o1 * o1;
                    h_[nh][i][j] = aH[i][j][0];
                }
                atomicAdd(&red[f], s0);
                atomicAdd(&red[3072 + f], q0);
                atomicAdd(&red[512 + f], s1);
                atomicAdd(&red[3072 + 512 + f], q1);
            } else {
                float a0 = coef[f],       c0 = coef[3072 + f];
                float a1 = coef[512 + f], c1 = coef[3584 + f];
                #pragma unroll
                for (int i = 0; i < 4; ++i) {
                    float o0 = v0_[i][j] + u_[i][j];
                    float o1 = aV[i][j][0] + u_[i][j];
                    float m1 = fminf(fmaxf(a0 * o0 + c0, 0.f),
                                     fmaxf(a1 * o1 + c1, 0.f));
                    hm[nh][i][j] = (unsigned)f2b(aH[i][j][0])
                                 | ((unsigned)f2b(m1) << 16);
                }
            }
        }
    }

    // ================= t phase (K=512, full N, gathered once) =================
    {
        f32x4 aT[4][8];
        #pragma unroll
        for (int i = 0; i < 4; ++i)
            #pragma unroll
            for (int j = 0; j < 8; ++j)
                aT[i][j] = (f32x4){0.f, 0.f, 0.f, 0.f};
        uint4 ap0, ap1;
        loadA_t(0, ap0, ap1);
        writeA_t(ap0, ap1);
        #pragma unroll 1
        for (int ch = 0; ch < 8; ++ch) {
            if (ch < 7) loadA_t(ch + 1, ap0, ap1);          // prefetch
            stageB512(768 + ch * 64);
            __syncthreads();
            mma1(aT);
            __syncthreads();
            if (ch < 7) writeA_t(ap0, ap1);                 // write-late
        }

        if constexpr (!FINAL) {
            #pragma unroll
            for (int j = 0; j < 8; ++j) {
                int f = ((j >> 2) << 8) + wnb + ((j & 3) << 4) + l16;
                float s[4] = {0.f, 0.f, 0.f, 0.f}, q[4] = {0.f, 0.f, 0.f, 0.f};
                #pragma unroll
                for (int i = 0; i < 4; ++i) {
                    float h = h_[j >> 2][i][j & 3];
                    #pragma unroll
                    for (int r = 0; r < 4; ++r) {
                        float v = aT[i][j][r] + h;
                        s[r] += v; q[r] += v * v;
                    }
                }
                #pragma unroll
                for (int r = 0; r < 4; ++r) {
                    atomicAdd(&red[(2 + r) * 512 + f], s[r]);
                    atomicAdd(&red[3072 + (2 + r) * 512 + f], q[r]);
                }
            }
            __syncthreads();
            for (int i = tid; i < 3072; i += 512) {
                atomicAdd(&accum[i], red[i]);
                atomicAdd(&accum[3072 + i], red[3072 + i]);
            }
        } else {
            float dp[4] = {0.f, 0.f, 0.f, 0.f};
            #pragma unroll
            for (int j = 0; j < 8; ++j) {
                int f = ((j >> 2) << 8) + wnb + ((j & 3) << 4) + l16;
                float a[4], c[4];
                #pragma unroll
                for (int r = 0; r < 4; ++r) {
                    a[r] = coef[(2 + r) * 512 + f];
                    c[r] = coef[3072 + (2 + r) * 512 + f];
                }
                float fw = fcw[f];
                #pragma unroll
                for (int i = 0; i < 4; ++i) {
                    unsigned u = hm[j >> 2][i][j & 3];
                    float h  = b2f((unsigned short)(u & 0xffffu));
                    float m1 = b2f((unsigned short)(u >> 16));
                    float mv = 1e30f;
                    #pragma unroll
                    for (int r = 0; r < 4; ++r)
                        mv = fminf(mv, fmaxf(a[r] * (aT[i][j][r] + h) + c[r], 0.f));
                    dp[i] += fminf(mv, m1) * fw;
                }
            }
            #pragma unroll
            for (int i = 0; i < 4; ++i) {
                float v = dp[i];
                v += __shfl_xor(v, 1); v += __shfl_xor(v, 2);
                v += __shfl_xor(v, 4); v += __shfl_xor(v, 8);
                if (l16 == 0)
                    atomicAdd(&outacc[b0 + (wmb >> 2) + i * 4 + quad], v);
            }
        }
    }
}

__global__ void bncoef_kernel(const float* __restrict__ accum,
                              const float* __restrict__ g1, const float* __restrict__ be1,
                              const float* __restrict__ g2, const float* __restrict__ be2,
                              float* __restrict__ coef)
{
    int id = blockIdx.x * 256 + threadIdx.x;
    if (id >= 3072) return;
    int kw = id >> 9, f = id & 511;
    float mean = accum[id] * (1.f / BATCH);
    float var  = accum[3072 + id] * (1.f / BATCH) - mean * mean;
    float g  = kw < 2 ? g1[f] : g2[f];
    float be = kw < 2 ? be1[f] : be2[f];
    float a  = g * rsqrtf(var + 1e-5f);
    coef[id] = a;
    coef[3072 + id] = be - a * mean;
}

__global__ void finish_kernel(const float* __restrict__ outacc,
                              const float* __restrict__ fcb, float* __restrict__ out)
{
    int b = blockIdx.x * 256 + threadIdx.x;
    if (b < BATCH)
        out[b] = outacc[b] + fcb[0];
}

extern "C" void kernel_launch(void* const* d_in, const int* in_sizes, int n_in,
                              void* d_out, int out_size, void* d_ws, size_t ws_size,
                              hipStream_t stream)
{
    (void)in_sizes; (void)n_in; (void)out_size; (void)ws_size;
    const int*   x    = (const int*)  d_in[0];
    const float* embR = (const float*)d_in[2];    // 50000 x 256 f32
    const float* embV = (const float*)d_in[3];    // 50000 x 256 f32
    const float* W1   = (const float*)d_in[4];    // 512 x 2 x 256 f32
    const float* g1   = (const float*)d_in[6];
    const float* be1  = (const float*)d_in[7];
    const float* W2   = (const float*)d_in[8];    // 512 x 5 x 256 f32
    const float* g2   = (const float*)d_in[10];
    const float* be2  = (const float*)d_in[11];
    const float* fcw  = (const float*)d_in[12];   // 512 f32
    const float* fcb  = (const float*)d_in[13];

    char* wsb = (char*)d_ws;
    float* accum  = (float*)wsb;                          //        0: 24 KB
    float* coef   = accum + 6144;                         //    24576: 24 KB
    float* outacc = coef + 6144;                          //    49152: 128 KB
    bf16*  Wbf1   = (bf16*)(wsb + 180224);                //   512 KB
    bf16*  Wbf2   = (bf16*)(wsb + 704512);                //  1.25 MB
    bf16*  embRb  = (bf16*)(wsb + 2015232);               //  25.6 MB
    bf16*  embVb  = (bf16*)(wsb + 27615232);              //  -> 53215232 (53.2MB)

    hipMemsetAsync(accum, 0, 6144 * sizeof(float), stream);
    hipMemsetAsync(outacc, 0, BATCH * sizeof(float), stream);
    cvt_kernel<<<256, 256, 0, stream>>>(W1, (unsigned short*)Wbf1, 65536);
    cvt_kernel<<<640, 256, 0, stream>>>(W2, (unsigned short*)Wbf2, 163840);
    cvt_kernel<<<12500, 256, 0, stream>>>(embR, (unsigned short*)embRb, 3200000);
    cvt_kernel<<<12500, 256, 0, stream>>>(embV, (unsigned short*)embVb, 3200000);

    pass_kernel<false><<<1024, 512, 0, stream>>>(
        x, embRb, embVb, Wbf1, Wbf2, accum, nullptr, nullptr, nullptr);
    bncoef_kernel<<<12, 256, 0, stream>>>(accum, g1, be1, g2, be2, coef);
    pass_kernel<true><<<1024, 512, 0, stream>>>(
        x, embRb, embVb, Wbf1, Wbf2, nullptr, coef, fcw, outacc);
    finish_kernel<<<128, 256, 0, stream>>>(outacc, fcb, (float*)d_out);
}

// Round 5
// 896.093 us; speedup vs baseline: 2.9965x; 2.9965x over previous
//
#include <hip/hip_runtime.h>
#include <hip/hip_bf16.h>

// HINGE_56985626083396 — fused embedding-conv-BN-min-FC forward on MI355X.
//
// Round-14: r13's demand==unique idea re-done in r10's spill-free register
// shape. r13 failed on REGISTER SPILLS (WRITE 4.1GB scratch: acc[4][8]+
// aH/aV > 128-reg cap), not on the algorithm. This round:
//   - block = 32 batches x 256 n (2 n-siblings, same-XCD via swizzle - the
//     r10 shape whose L2 absorbed sibling duplication), acc[4][4] only.
//   - ONE kernel, two sequential phases reusing acc:
//       G1 phase: K=512 [fv_kk|fr0], 64 real rows mirrored to 128 (waves
//                 wv>=4 compute duplicates, epilogue uses wv<4 only).
//       T phase:  K=1280 full win2 [fv0|fr0|fv1|kr_kk|kv_kk], RPB=4 ->
//                 acc reg r == window 2+r WITH hrt folded in. No Hbuf.
//   - stats pass: G1 -> red(LDS) windows 0,1; T -> windows 2..5; one flush.
//     final pass: G1 -> m1 bf16 in LDS (16KB, no min1 buffer); T -> m2 =
//                 min_r relu(a_r*acc_r+c_r), min with m1, dot fcw -> outacc.
//   - Hbuf/min1 eliminated -> bf16 tables (51.2 MB) always fit workspace
//     (proven >= 69.1 MB): half the gather bytes, L3-retainable footprint.
// 5 gemm dispatches -> 2. Demand/pass ~184 MB x2 siblings (L2-absorbed),
// unique 51.2 MB. conv biases skipped (BN mean-subtraction cancels).
// LDS 73.2 KB -> 2 blocks/CU; launch_bounds(512,2) -> 128-reg cap, need ~100.

typedef __hip_bfloat16 bf16;
typedef short bf16x8 __attribute__((ext_vector_type(8)));   // 8 bf16 in 4 VGPRs
typedef float f32x4 __attribute__((ext_vector_type(4)));

#define BATCH 32768

__device__ __forceinline__ unsigned short f2b(float f) {
    union { float f; unsigned u; } v; v.f = f;
    unsigned r = v.u + 0x7fffu + ((v.u >> 16) & 1u);   // round-to-nearest-even
    return (unsigned short)(r >> 16);
}

__device__ __forceinline__ float b2f(unsigned short u) {
    union { unsigned x; float f; } v; v.x = ((unsigned)u) << 16;
    return v.f;
}

__global__ __launch_bounds__(256)
void cvt_kernel(const float* __restrict__ src, unsigned short* __restrict__ dst, int n4)
{
    int i = blockIdx.x * 256 + threadIdx.x;
    if (i >= n4) return;
    float4 v = ((const float4*)src)[i];
    ushort4 h;
    h.x = f2b(v.x); h.y = f2b(v.y); h.z = f2b(v.z); h.w = f2b(v.w);
    ((ushort4*)dst)[i] = h;
}

// One block: 32 batches x 256 n-cols. 512 threads, 8 waves (2 m x 4 n),
// wave tile 64x64. Grid 2048 = 1024 m-tiles x 2 n; swizzle keeps the two
// n-siblings of a batch group on the same XCD, 8 dispatch-slots apart.
template<bool FINAL>
__global__ __launch_bounds__(512, 2)
void pass_kernel(const int* __restrict__ x, const bf16* __restrict__ embR,
                 const bf16* __restrict__ embV, const bf16* __restrict__ W1b,
                 const bf16* __restrict__ W2b, float* __restrict__ accum,
                 const float* __restrict__ coef, const float* __restrict__ fcw,
                 float* __restrict__ outacc)
{
    __shared__ __align__(16) short Ash[128 * 72];   // +8 pad per row
    __shared__ __align__(16) short Bsh[256 * 72];
    __shared__ int xsh[384];
    __shared__ __align__(16) float scr[4096];       // red (stats) / m1s (final)

    const int tid = threadIdx.x;
    const int lin = blockIdx.x;
    const int mt  = (lin >> 4) * 8 + (lin & 7);     // m-tile 0..1023
    const int nb  = ((lin >> 3) & 1) * 256;         // n-half
    const int b0  = mt * 32;

    for (int i = tid; i < 384; i += 512) xsh[i] = x[b0 * 12 + i];
    if constexpr (!FINAL)
        for (int i = tid; i < 3072; i += 512) scr[i] = 0.f;
    __syncthreads();

    const int lane = tid & 63;
    const int wv   = tid >> 6;                      // 0..7
    const int wmb  = (wv >> 2) * 64;                // wave m-offset (0/64)
    const int wnb  = (wv & 3) * 64;                 // wave n-offset
    const int quad = lane >> 4;
    const int l16  = lane & 15;

    // ---- staging helpers ----
    auto stageA = [&](int seg, int col, bool g1) {
        #pragma unroll
        for (int it = 0; it < 2; ++it) {
            int flat = tid + it * 512;              // 0..1023
            int row  = flat >> 3;
            int off8 = flat & 7;
            int idx; const bf16* tab;
            if (g1) {                               // 64 rows mirrored x2
                int vr = row & 63, bl = vr >> 1, kk = vr & 1;
                if (seg == 0) { idx = xsh[bl * 12 + 2 * kk + 1]; tab = embV; }
                else          { idx = xsh[bl * 12];              tab = embR; }
            } else {                                // full win2, RPB=4
                int bl = row >> 2, kk = row & 3;
                switch (seg) {
                    case 0:  idx = xsh[bl * 12 + 1];          tab = embV; break;
                    case 1:  idx = xsh[bl * 12 + 0];          tab = embR; break;
                    case 2:  idx = xsh[bl * 12 + 3];          tab = embV; break;
                    case 3:  idx = xsh[bl * 12 + 2 * kk + 4]; tab = embR; break;
                    default: idx = xsh[bl * 12 + 2 * kk + 5]; tab = embV; break;
                }
            }
            uint4 v = *((const uint4*)(tab + (size_t)idx * 256 + col) + off8);
            *(uint4*)&Ash[row * 72 + off8 * 8] = v;
        }
    };
    auto stageB = [&](const bf16* W, int stride, int col) {
        #pragma unroll
        for (int it = 0; it < 4; ++it) {
            int flat = tid + it * 512;              // 0..2047
            int fr   = flat >> 3;
            int off8 = flat & 7;
            uint4 v = *((const uint4*)(W + (size_t)(nb + fr) * stride + col) + off8);
            *(uint4*)&Bsh[fr * 72 + off8 * 8] = v;
        }
    };
    auto mma = [&](f32x4 (&acc)[4][4]) {
        #pragma unroll
        for (int ks = 0; ks < 64; ks += 32) {
            bf16x8 af[4], bf_[4];
            #pragma unroll
            for (int t = 0; t < 4; ++t)
                af[t]  = *(const bf16x8*)&Ash[(wmb + t * 16 + l16) * 72 + ks + quad * 8];
            #pragma unroll
            for (int t = 0; t < 4; ++t)
                bf_[t] = *(const bf16x8*)&Bsh[(wnb + t * 16 + l16) * 72 + ks + quad * 8];
            #pragma unroll
            for (int i = 0; i < 4; ++i)
                #pragma unroll
                for (int j = 0; j < 4; ++j)
                    acc[i][j] = __builtin_amdgcn_mfma_f32_16x16x32_bf16(
                        af[i], bf_[j], acc[i][j], 0, 0, 0);
        }
    };

    f32x4 acc[4][4];

    // ================= G1 phase: K=512, windows 0,1 =================
    #pragma unroll
    for (int i = 0; i < 4; ++i)
        #pragma unroll
        for (int j = 0; j < 4; ++j)
            acc[i][j] = (f32x4){0.f, 0.f, 0.f, 0.f};
    #pragma unroll 1
    for (int ch = 0; ch < 8; ++ch) {
        stageA(ch >> 2, (ch & 3) * 64, true);
        stageB(W1b, 512, ch * 64);
        __syncthreads();
        mma(acc);
        __syncthreads();
    }
    // epilogue: rows m = i*16+quad*4+r (wmb=0 waves only); bl=m>>1, kk=r&1.
    if (wv < 4) {
        if constexpr (!FINAL) {
            #pragma unroll
            for (int j = 0; j < 4; ++j) {
                int fl = wnb + j * 16 + l16;
                #pragma unroll
                for (int r = 0; r < 4; ++r) {
                    float sr = 0.f, qr = 0.f;
                    #pragma unroll
                    for (int i = 0; i < 4; ++i) {
                        float v = acc[i][j][r];
                        sr += v; qr += v * v;
                    }
                    atomicAdd(&scr[(r & 1) * 256 + fl], sr);
                    atomicAdd(&scr[1536 + (r & 1) * 256 + fl], qr);
                }
            }
        } else {
            unsigned short* m1s = (unsigned short*)scr;
            #pragma unroll
            for (int j = 0; j < 4; ++j) {
                int fl = wnb + j * 16 + l16, f = nb + fl;
                float a0 = coef[f],       c0 = coef[3072 + f];
                float a1 = coef[512 + f], c1 = coef[3584 + f];
                #pragma unroll
                for (int i = 0; i < 4; ++i)
                    #pragma unroll
                    for (int rp = 0; rp < 2; ++rp) {
                        int bl = i * 8 + quad * 2 + rp;
                        float v0 = fmaxf(a0 * acc[i][j][rp * 2]     + c0, 0.f);
                        float v1 = fmaxf(a1 * acc[i][j][rp * 2 + 1] + c1, 0.f);
                        m1s[bl * 256 + fl] = f2b(fminf(v0, v1));
                    }
            }
        }
    }

    // ============ T phase: K=1280 full win2, windows 2..5 ============
    #pragma unroll
    for (int i = 0; i < 4; ++i)
        #pragma unroll
        for (int j = 0; j < 4; ++j)
            acc[i][j] = (f32x4){0.f, 0.f, 0.f, 0.f};
    #pragma unroll 1
    for (int ch = 0; ch < 20; ++ch) {
        stageA(ch >> 2, (ch & 3) * 64, false);
        stageB(W2b, 1280, ch * 64);
        __syncthreads();
        mma(acc);
        __syncthreads();
    }
    // acc reg r == window 2+r (hrt included); batch = b0+(wmb>>2)+i*4+quad.
    if constexpr (!FINAL) {
        #pragma unroll
        for (int j = 0; j < 4; ++j) {
            int fl = wnb + j * 16 + l16;
            #pragma unroll
            for (int r = 0; r < 4; ++r) {
                float sr = 0.f, qr = 0.f;
                #pragma unroll
                for (int i = 0; i < 4; ++i) {
                    float v = acc[i][j][r];
                    sr += v; qr += v * v;
                }
                atomicAdd(&scr[(2 + r) * 256 + fl], sr);
                atomicAdd(&scr[1536 + (2 + r) * 256 + fl], qr);
            }
        }
        __syncthreads();
        for (int i2 = tid; i2 < 1536; i2 += 512) {
            int kw = i2 >> 8, fl = i2 & 255;
            atomicAdd(&accum[kw * 512 + nb + fl], scr[i2]);
            atomicAdd(&accum[3072 + kw * 512 + nb + fl], scr[1536 + i2]);
        }
    } else {
        const unsigned short* m1s = (const unsigned short*)scr;
        float dp[4] = {0.f, 0.f, 0.f, 0.f};
        #pragma unroll
        for (int j = 0; j < 4; ++j) {
            int fl = wnb + j * 16 + l16, f = nb + fl;
            float a[4], c[4];
            #pragma unroll
            for (int r = 0; r < 4; ++r) {
                a[r] = coef[(2 + r) * 512 + f];
                c[r] = coef[3072 + (2 + r) * 512 + f];
            }
            float fw = fcw[f];
            #pragma unroll
            for (int i = 0; i < 4; ++i) {
                int bb = (wmb >> 2) + i * 4 + quad;
                float mv = 1e30f;
                #pragma unroll
                for (int r = 0; r < 4; ++r)
                    mv = fminf(mv, fmaxf(a[r] * acc[i][j][r] + c[r], 0.f));
                mv = fminf(mv, b2f(m1s[bb * 256 + fl]));
                dp[i] += mv * fw;
            }
        }
        #pragma unroll
        for (int i = 0; i < 4; ++i) {
            float v = dp[i];
            v += __shfl_xor(v, 1); v += __shfl_xor(v, 2);
            v += __shfl_xor(v, 4); v += __shfl_xor(v, 8);
            if (l16 == 0)
                atomicAdd(&outacc[b0 + (wmb >> 2) + i * 4 + quad], v);
        }
    }
}

__global__ void bncoef_kernel(const float* __restrict__ accum,
                              const float* __restrict__ g1, const float* __restrict__ be1,
                              const float* __restrict__ g2, const float* __restrict__ be2,
                              float* __restrict__ coef)
{
    int id = blockIdx.x * 256 + threadIdx.x;
    if (id >= 3072) return;
    int kw = id >> 9, f = id & 511;
    float mean = accum[id] * (1.f / BATCH);
    float var  = accum[3072 + id] * (1.f / BATCH) - mean * mean;
    float g  = kw < 2 ? g1[f] : g2[f];
    float be = kw < 2 ? be1[f] : be2[f];
    float a  = g * rsqrtf(var + 1e-5f);
    coef[id] = a;
    coef[3072 + id] = be - a * mean;
}

__global__ void finish_kernel(const float* __restrict__ outacc,
                              const float* __restrict__ fcb, float* __restrict__ out)
{
    int b = blockIdx.x * 256 + threadIdx.x;
    if (b < BATCH)
        out[b] = outacc[b] + fcb[0];
}

extern "C" void kernel_launch(void* const* d_in, const int* in_sizes, int n_in,
                              void* d_out, int out_size, void* d_ws, size_t ws_size,
                              hipStream_t stream)
{
    (void)in_sizes; (void)n_in; (void)out_size; (void)ws_size;
    const int*   x    = (const int*)  d_in[0];
    const float* embR = (const float*)d_in[2];    // 50000 x 256 f32
    const float* embV = (const float*)d_in[3];    // 50000 x 256 f32
    const float* W1   = (const float*)d_in[4];    // 512 x 2 x 256 f32
    const float* g1   = (const float*)d_in[6];
    const float* be1  = (const float*)d_in[7];
    const float* W2   = (const float*)d_in[8];    // 512 x 5 x 256 f32
    const float* g2   = (const float*)d_in[10];
    const float* be2  = (const float*)d_in[11];
    const float* fcw  = (const float*)d_in[12];   // 512 f32
    const float* fcb  = (const float*)d_in[13];

    char* wsb = (char*)d_ws;
    float* accum  = (float*)wsb;                          //        0: 24 KB
    float* coef   = accum + 6144;                         //    24576: 24 KB
    float* outacc = coef + 6144;                          //    49152: 128 KB
    bf16*  Wbf1   = (bf16*)(wsb + 180224);                //   512 KB
    bf16*  Wbf2   = (bf16*)(wsb + 704512);                //  1.25 MB
    bf16*  embRb  = (bf16*)(wsb + 2015232);               //  25.6 MB
    bf16*  embVb  = (bf16*)(wsb + 27615232);              //  -> 53215232 (53.2MB)

    hipMemsetAsync(accum, 0, 6144 * sizeof(float), stream);
    hipMemsetAsync(outacc, 0, BATCH * sizeof(float), stream);
    cvt_kernel<<<256, 256, 0, stream>>>(W1, (unsigned short*)Wbf1, 65536);
    cvt_kernel<<<640, 256, 0, stream>>>(W2, (unsigned short*)Wbf2, 163840);
    cvt_kernel<<<12500, 256, 0, stream>>>(embR, (unsigned short*)embRb, 3200000);
    cvt_kernel<<<12500, 256, 0, stream>>>(embV, (unsigned short*)embVb, 3200000);

    pass_kernel<false><<<2048, 512, 0, stream>>>(
        x, embRb, embVb, Wbf1, Wbf2, accum, nullptr, nullptr, nullptr);
    bncoef_kernel<<<12, 256, 0, stream>>>(accum, g1, be1, g2, be2, coef);
    pass_kernel<true><<<2048, 512, 0, stream>>>(
        x, embRb, embVb, Wbf1, Wbf2, nullptr, coef, fcw, outacc);
    finish_kernel<<<128, 256, 0, stream>>>(outacc, fcb, (float*)d_out);
}